// Round 5
// baseline (548.773 us; speedup 1.0000x reference)
//
#include <hip/hip_runtime.h>
#include <math.h>

// Fuzzy capsule routing, MI355X — round 5: DS-pipe offload.
// mw coefficient rows live in GLOBAL memory (VMEM broadcast, L2-hot), built
// once-per-n by a last-block tail reduction. Sigma folds dist3 into phase 1.

#define NB 64
#define NK 20
#define NSPLIT 16
#define CPB 2
#define LPST 20           // lp row stride (floats)
#define RST 132           // r_s row stride
#define MROW 20           // mw row: [0..15]=-2Wg, [16]=|g|^2
#define QROW 12           // MQ row: [0..9]=W.W^T pairs

__device__ __forceinline__ float frcp(float x){ return __builtin_amdgcn_rcpf(x); }
__device__ __forceinline__ float4 ldg4(const float* p){ return *(const float4*)p; }

// build g-dependent rows for one n: dst[(c*NK+k)*MROW]
__device__ __forceinline__ void build_rows(const float* __restrict__ wgt,
                                           const float* g_s,
                                           float* __restrict__ dst, int tid)
{
    for (int row = tid; row < 32*NK; row += 256){
        const int c = row / NK, k = row - c*NK;
        const float* W = wgt + k*512 + c*16;
        float w[16];
        {
            float4 a = ldg4(W+0), b = ldg4(W+4), cc = ldg4(W+8), d = ldg4(W+12);
            w[0]=a.x; w[1]=a.y; w[2]=a.z; w[3]=a.w;
            w[4]=b.x; w[5]=b.y; w[6]=b.z; w[7]=b.w;
            w[8]=cc.x; w[9]=cc.y; w[10]=cc.z; w[11]=cc.w;
            w[12]=d.x; w[13]=d.y; w[14]=d.z; w[15]=d.w;
        }
        float g[16];
        #pragma unroll
        for (int x=0;x<16;x++) g[x] = g_s[k*16+x];
        float out[17];
        #pragma unroll
        for (int i=0;i<4;i++)
            #pragma unroll
            for (int j=0;j<4;j++){
                float a = w[j*4+0]*g[i*4+0] + w[j*4+1]*g[i*4+1]
                        + w[j*4+2]*g[i*4+2] + w[j*4+3]*g[i*4+3];
                out[i*4+j] = -2.f*a;
            }
        float cst = 0.f;
        #pragma unroll
        for (int x=0;x<16;x++) cst += g[x]*g[x];
        out[16] = cst;
        float* dp = dst + row*MROW;
        *(float4*)(dp+0)  = make_float4(out[0],out[1],out[2],out[3]);
        *(float4*)(dp+4)  = make_float4(out[4],out[5],out[6],out[7]);
        *(float4*)(dp+8)  = make_float4(out[8],out[9],out[10],out[11]);
        *(float4*)(dp+12) = make_float4(out[12],out[13],out[14],out[15]);
        *(float4*)(dp+16) = make_float4(out[16],0.f,0.f,0.f);
    }
}

// ---------------- prep: mw(g0) for all n; MQ once; zero counters ----------------
__global__ __launch_bounds__(256)
void k_prep0(const float* __restrict__ g_in, const float* __restrict__ wgt,
             float* __restrict__ mwA, float* __restrict__ MQ, int* __restrict__ cnt)
{
    const int n = blockIdx.x, tid = threadIdx.x;
    __shared__ __align__(16) float g_s[NK*16];
    for (int t = tid; t < NK*16; t += 256) g_s[t] = g_in[n*NK*16 + t];
    __syncthreads();
    build_rows(wgt, g_s, mwA + (size_t)n*640*MROW, tid);
    if (n == 0){
        for (int row = tid; row < 640; row += 256){
            const int c = row / NK, k = row - c*NK;
            const float* W = wgt + k*512 + c*16;
            float w[16];
            {
                float4 a = ldg4(W+0), b = ldg4(W+4), cc = ldg4(W+8), d = ldg4(W+12);
                w[0]=a.x; w[1]=a.y; w[2]=a.z; w[3]=a.w;
                w[4]=b.x; w[5]=b.y; w[6]=b.z; w[7]=b.w;
                w[8]=cc.x; w[9]=cc.y; w[10]=cc.z; w[11]=cc.w;
                w[12]=d.x; w[13]=d.y; w[14]=d.z; w[15]=d.w;
            }
            float q[12]; int p = 0;
            #pragma unroll
            for (int j=0;j<4;j++)
                #pragma unroll
                for (int jp=j;jp<4;jp++){
                    float a = w[j*4+0]*w[jp*4+0] + w[j*4+1]*w[jp*4+1]
                            + w[j*4+2]*w[jp*4+2] + w[j*4+3]*w[jp*4+3];
                    q[p++] = (j==jp)? a : 2.f*a;
                }
            q[10]=0.f; q[11]=0.f;
            float* dp = MQ + row*QROW;
            *(float4*)(dp+0) = make_float4(q[0],q[1],q[2],q[3]);
            *(float4*)(dp+4) = make_float4(q[4],q[5],q[6],q[7]);
            *(float4*)(dp+8) = make_float4(q[8],q[9],0.f,0.f);
        }
    }
    if (tid < 3) atomicExch(&cnt[tid*64 + n], 0);
}

// ---------------- routing iteration ----------------
// MODE 0: tail writes mwOut(g_new).  MODE 1: tail writes mwD + s3inv + g3w.
template<int MODE>
__global__ __launch_bounds__(256, 4)
void k_route(const float* __restrict__ l, const float* __restrict__ wgt,
             const float* __restrict__ MQ, const float* __restrict__ mwIn,
             float* __restrict__ P, int* __restrict__ cnt,
             float* __restrict__ mwOut, float* __restrict__ s3inv,
             float* __restrict__ g3w)
{
    const int split = blockIdx.x, n = blockIdx.y, tid = threadIdx.x;
    const int c0 = split*CPB;

    __shared__ __align__(16) float lp_s[CPB*64*LPST];   // 2560
    __shared__ __align__(16) float r_s[NK*RST];         // 2640
    __shared__ __align__(16) float red_s[4*NK*MROW];    // 1600
    __shared__ __align__(16) float wt_s[NK*33];         // 660
    __shared__ __align__(16) float tmp_s[NK*17];
    __shared__ __align__(16) float g_s[NK*16];
    __shared__ int tail_flag;

    for (int t = tid; t < NK*32; t += 256){
        int k = t>>5, rest = t&31;
        wt_s[k*33 + rest] = wgt[k*512 + c0*16 + rest];
    }
    const float* lsrc = l + ((size_t)n*32 + c0)*1024;
    #pragma unroll
    for (int i=0;i<8;i++){
        int t = i*256 + tid;
        int cl = t>>10, dd = (t>>6)&15, wh = t&63;
        lp_s[(cl*64 + wh)*LPST + dd] = lsrc[t];
    }
    __syncthreads();

    // ---- phase 1: thread=(m, khalf); mw/MQ from global (broadcast) ----
    {
        const int m = tid >> 1, kh = tid & 1;
        const float* lpr = &lp_s[m*LPST];
        float lp[16];
        #pragma unroll
        for (int q=0;q<4;q++){
            float4 v = *(const float4*)&lpr[q*4];
            lp[q*4+0]=v.x; lp[q*4+1]=v.y; lp[q*4+2]=v.z; lp[q*4+3]=v.w;
        }
        float QS[10];
        {
            int p=0;
            #pragma unroll
            for (int j=0;j<4;j++)
                #pragma unroll
                for (int jp=j;jp<4;jp++){
                    QS[p] = lp[j]*lp[jp] + lp[4+j]*lp[4+jp]
                          + lp[8+j]*lp[8+jp] + lp[12+j]*lp[12+jp];
                    p++;
                }
        }
        const int cl = tid >> 7;   // wave-uniform
        const int rb = __builtin_amdgcn_readfirstlane((n*32 + c0 + cl)*NK);
        const int qb = __builtin_amdgcn_readfirstlane((c0 + cl)*NK);
        const float* mwb = mwIn + (size_t)(rb + kh*10)*MROW;
        const float* mqb = MQ   + (size_t)(qb + kh*10)*QROW;
        float invs[10];
        float rd = 0.f;
        #pragma unroll
        for (int i=0;i<10;i++){
            const float* row = mwb + i*MROW;
            const float* mq  = mqb + i*QROW;
            float4 w0 = ldg4(row+0), w1 = ldg4(row+4), w2 = ldg4(row+8), w3 = ldg4(row+12);
            float  c2 = row[16];
            float4 m0 = ldg4(mq+0), m1 = ldg4(mq+4);
            float2 m2 = *(const float2*)(mq+8);
            float rn = c2;
            rn += m0.x*QS[0] + m0.y*QS[1] + m0.z*QS[2] + m0.w*QS[3]
                + m1.x*QS[4] + m1.y*QS[5] + m1.z*QS[6] + m1.w*QS[7]
                + m2.x*QS[8] + m2.y*QS[9];
            rn += w0.x*lp[0] + w0.y*lp[1] + w0.z*lp[2] + w0.w*lp[3]
                + w1.x*lp[4] + w1.y*lp[5] + w1.z*lp[6] + w1.w*lp[7]
                + w2.x*lp[8] + w2.y*lp[9] + w2.z*lp[10]+ w2.w*lp[11]
                + w3.x*lp[12]+ w3.y*lp[13]+ w3.z*lp[14]+ w3.w*lp[15];
            float inv = frcp(rn);
            invs[i] = inv;
            rd += inv;
        }
        rd += __shfl_xor(rd, 1, 64);
        float ird = frcp(rd);
        #pragma unroll
        for (int i=0;i<10;i++){
            float t0 = invs[i]*ird;
            r_s[(kh*10+i)*RST + m] = t0*t0;
        }
    }
    __syncthreads();

    // ---- phase 3: T[w,k,ij] = sum_m r*lp ----
    const int k3 = tid & 31, mi = tid >> 5;
    const int kk = (k3 < NK)? k3 : k3 - NK;
    const int mbase = mi*16;
    float T[16]; float sacc = 0.f;
    #pragma unroll
    for (int d=0;d<16;d++) T[d]=0.f;

    auto acc_m = [&](float r, int m){
        const float* lr = &lp_s[m*LPST];
        float4 v0 = *(const float4*)&lr[0];
        float4 v1 = *(const float4*)&lr[4];
        float4 v2 = *(const float4*)&lr[8];
        float4 v3 = *(const float4*)&lr[12];
        T[0]+=r*v0.x; T[1]+=r*v0.y; T[2]+=r*v0.z; T[3]+=r*v0.w;
        T[4]+=r*v1.x; T[5]+=r*v1.y; T[6]+=r*v1.z; T[7]+=r*v1.w;
        T[8]+=r*v2.x; T[9]+=r*v2.y; T[10]+=r*v2.z; T[11]+=r*v2.w;
        T[12]+=r*v3.x; T[13]+=r*v3.y; T[14]+=r*v3.z; T[15]+=r*v3.w;
        sacc += r;
    };
    #pragma unroll
    for (int j4=0;j4<4;j4++){
        float4 rv = *(const float4*)&r_s[kk*RST + mbase + j4*4];
        acc_m(rv.x, mbase + j4*4 + 0);
        acc_m(rv.y, mbase + j4*4 + 1);
        acc_m(rv.z, mbase + j4*4 + 2);
        acc_m(rv.w, mbase + j4*4 + 3);
    }
    #pragma unroll
    for (int d=0;d<16;d++) T[d] += __shfl_xor(T[d], 32, 64);
    sacc += __shfl_xor(sacc, 32, 64);
    if ((k3 < NK) && !(tid & 32)){
        float* row = &red_s[((tid>>6)*NK + k3)*MROW];
        *(float4*)(row+0)  = make_float4(T[0],T[1],T[2],T[3]);
        *(float4*)(row+4)  = make_float4(T[4],T[5],T[6],T[7]);
        *(float4*)(row+8)  = make_float4(T[8],T[9],T[10],T[11]);
        *(float4*)(row+12) = make_float4(T[12],T[13],T[14],T[15]);
        row[16] = sacc;
    }
    __syncthreads();

    // ---- u-contract + P write ----
    for (int t = tid; t < NK*17; t += 256){
        int k = t/17, x = t - k*17;
        float acc = 0.f;
        if (x == 16){
            #pragma unroll
            for (int w=0;w<4;w++) acc += red_s[(w*NK+k)*MROW + 16];
        } else {
            int i = x>>2, o = x&3;
            #pragma unroll
            for (int w=0;w<4;w++){
                int cl = w>>1;
                #pragma unroll
                for (int j=0;j<4;j++)
                    acc += red_s[(w*NK+k)*MROW + i*4+j] * wt_s[k*33 + cl*16 + j*4+o];
            }
        }
        P[(size_t)(n*NSPLIT+split)*340 + t] = acc;
    }

    // ---- last-block tail: g reduce + mw build ----
    __threadfence();
    __syncthreads();
    if (tid == 0){
        int old = atomicAdd(&cnt[n], 1);
        tail_flag = (old == NSPLIT-1);
    }
    __syncthreads();
    if (!tail_flag) return;
    __threadfence();
    for (int t = tid; t < 340; t += 256){
        float acc = 0.f;
        #pragma unroll
        for (int s=0;s<NSPLIT;s++) acc += P[(size_t)(n*NSPLIT+s)*340 + t];
        tmp_s[t] = acc;
    }
    __syncthreads();
    for (int t = tid; t < 320; t += 256){
        int k = t>>4, d = t&15;
        g_s[t] = tmp_s[k*17 + d] / tmp_s[k*17 + 16];
    }
    __syncthreads();
    build_rows(wgt, g_s, mwOut + (size_t)n*640*MROW, tid);
    if (MODE == 1){
        if (tid < NK) s3inv[n*NK + tid] = 1.f / tmp_s[tid*17 + 16];
        for (int t = tid; t < 320; t += 256) g3w[n*320 + t] = g_s[t];
    }
}

// ---------------- sigma pass ----------------
__global__ __launch_bounds__(256, 4)
void k_sigma(const float* __restrict__ l, const float* __restrict__ MQ,
             const float* __restrict__ mw2, const float* __restrict__ mwD,
             const float* __restrict__ s3inv, float* __restrict__ PS)
{
    const int split = blockIdx.x, n = blockIdx.y, tid = threadIdx.x;
    const int c0 = split*CPB;

    __shared__ __align__(16) float lp_s[CPB*64*LPST];
    __shared__ __align__(16) float pr_s[NK*RST];
    __shared__ __align__(16) float red2[4*NK];

    const float* lsrc = l + ((size_t)n*32 + c0)*1024;
    #pragma unroll
    for (int i=0;i<8;i++){
        int t = i*256 + tid;
        int cl = t>>10, dd = (t>>6)&15, wh = t&63;
        lp_s[(cl*64 + wh)*LPST + dd] = lsrc[t];
    }
    __syncthreads();

    // ---- phase 1: r (from g2-rows) and dist3 (from g3-rows); store r*dist3 ----
    {
        const int m = tid >> 1, kh = tid & 1;
        const float* lpr = &lp_s[m*LPST];
        float lp[16];
        #pragma unroll
        for (int q=0;q<4;q++){
            float4 v = *(const float4*)&lpr[q*4];
            lp[q*4+0]=v.x; lp[q*4+1]=v.y; lp[q*4+2]=v.z; lp[q*4+3]=v.w;
        }
        float QS[10];
        {
            int p=0;
            #pragma unroll
            for (int j=0;j<4;j++)
                #pragma unroll
                for (int jp=j;jp<4;jp++){
                    QS[p] = lp[j]*lp[jp] + lp[4+j]*lp[4+jp]
                          + lp[8+j]*lp[8+jp] + lp[12+j]*lp[12+jp];
                    p++;
                }
        }
        const int cl = tid >> 7;
        const int rb = __builtin_amdgcn_readfirstlane((n*32 + c0 + cl)*NK);
        const int qb = __builtin_amdgcn_readfirstlane((c0 + cl)*NK);
        const float* m2b = mw2 + (size_t)(rb + kh*10)*MROW;
        const float* mDb = mwD + (size_t)(rb + kh*10)*MROW;
        const float* mqb = MQ  + (size_t)(qb + kh*10)*QROW;
        float invs[10], d3s[10];
        float rd = 0.f;
        #pragma unroll
        for (int i=0;i<10;i++){
            const float* r2 = m2b + i*MROW;
            const float* rD = mDb + i*MROW;
            const float* mq = mqb + i*QROW;
            float4 m0 = ldg4(mq+0), m1 = ldg4(mq+4);
            float2 m2v = *(const float2*)(mq+8);
            float qv = m0.x*QS[0] + m0.y*QS[1] + m0.z*QS[2] + m0.w*QS[3]
                     + m1.x*QS[4] + m1.y*QS[5] + m1.z*QS[6] + m1.w*QS[7]
                     + m2v.x*QS[8] + m2v.y*QS[9];
            float4 a0 = ldg4(r2+0), a1 = ldg4(r2+4), a2 = ldg4(r2+8), a3 = ldg4(r2+12);
            float rn = r2[16] + qv
                + a0.x*lp[0] + a0.y*lp[1] + a0.z*lp[2] + a0.w*lp[3]
                + a1.x*lp[4] + a1.y*lp[5] + a1.z*lp[6] + a1.w*lp[7]
                + a2.x*lp[8] + a2.y*lp[9] + a2.z*lp[10]+ a2.w*lp[11]
                + a3.x*lp[12]+ a3.y*lp[13]+ a3.z*lp[14]+ a3.w*lp[15];
            float4 b0 = ldg4(rD+0), b1 = ldg4(rD+4), b2 = ldg4(rD+8), b3 = ldg4(rD+12);
            float d3 = rD[16] + qv
                + b0.x*lp[0] + b0.y*lp[1] + b0.z*lp[2] + b0.w*lp[3]
                + b1.x*lp[4] + b1.y*lp[5] + b1.z*lp[6] + b1.w*lp[7]
                + b2.x*lp[8] + b2.y*lp[9] + b2.z*lp[10]+ b2.w*lp[11]
                + b3.x*lp[12]+ b3.y*lp[13]+ b3.z*lp[14]+ b3.w*lp[15];
            float inv = frcp(rn);
            invs[i] = inv; d3s[i] = d3;
            rd += inv;
        }
        rd += __shfl_xor(rd, 1, 64);
        float ird = frcp(rd);
        #pragma unroll
        for (int i=0;i<10;i++){
            float t0 = invs[i]*ird;
            pr_s[(kh*10+i)*RST + m] = (t0*t0)*d3s[i];
        }
    }
    __syncthreads();

    // ---- phase 3: per-k sum of products ----
    const int k3 = tid & 31, mi = tid >> 5;
    const int kk = (k3 < NK)? k3 : k3 - NK;
    float sig = 0.f;
    #pragma unroll
    for (int j4=0;j4<4;j4++){
        float4 rv = *(const float4*)&pr_s[kk*RST + mi*16 + j4*4];
        sig += rv.x + rv.y + rv.z + rv.w;
    }
    sig += __shfl_xor(sig, 32, 64);
    if ((k3 < NK) && !(tid & 32)) red2[(tid>>6)*NK + k3] = sig;
    __syncthreads();
    if (tid < NK){
        float acc = red2[tid] + red2[NK+tid] + red2[2*NK+tid] + red2[3*NK+tid];
        PS[(n*NSPLIT+split)*NK + tid] = acc * s3inv[n*NK + tid];
    }
}

// ---------------- finalize ----------------
__global__ __launch_bounds__(320)
void k_final(const float* __restrict__ PS, const float* __restrict__ g3w,
             const float* __restrict__ beta, float* __restrict__ out)
{
    const int n = blockIdx.x, tid = threadIdx.x;
    out[1280 + n*320 + tid] = g3w[n*320 + tid];
    if (tid < NK){
        float acc = 0.f;
        #pragma unroll
        for (int s=0;s<NSPLIT;s++) acc += PS[(n*NSPLIT+s)*NK + tid];
        float z = beta[tid] - 0.5f*logf(acc);   // LAMBDA = 1
        out[n*NK + tid] = 1.f/(1.f + expf(-z));
    }
}

extern "C" void kernel_launch(void* const* d_in, const int* in_sizes, int n_in,
                              void* d_out, int out_size, void* d_ws, size_t ws_size,
                              hipStream_t stream)
{
    const float* l    = (const float*)d_in[0];
    const float* g    = (const float*)d_in[1];
    const float* wgt  = (const float*)d_in[2];
    const float* beta = (const float*)d_in[3];
    float* out = (float*)d_out;
    float* ws  = (float*)d_ws;

    const size_t PSZ  = (size_t)NB * NSPLIT * 340;      // 348160
    const size_t MWSZ = (size_t)NB * 640 * MROW;        // 819200
    float* P    = ws;
    float* mwA  = P    + PSZ;
    float* mwB  = mwA  + MWSZ;
    float* mwD  = mwB  + MWSZ;
    float* MQ   = mwD  + MWSZ;                          // 7680
    float* s3i  = MQ   + 7680;                          // 1280
    float* g3w  = s3i  + 1280;                          // 20480
    float* PS   = g3w  + 20480;                         // 20480
    int*   cnt  = (int*)(PS + 20480);                   // 3*64 ints

    dim3 grid(NSPLIT, NB), blk(256);
    k_prep0<<<NB, 256, 0, stream>>>(g, wgt, mwA, MQ, cnt);
    k_route<0><<<grid, blk, 0, stream>>>(l, wgt, MQ, mwA, P, cnt + 0*64, mwB, nullptr, nullptr);
    k_route<0><<<grid, blk, 0, stream>>>(l, wgt, MQ, mwB, P, cnt + 1*64, mwA, nullptr, nullptr);
    k_route<1><<<grid, blk, 0, stream>>>(l, wgt, MQ, mwA, P, cnt + 2*64, mwD, s3i, g3w);
    k_sigma<<<grid, blk, 0, stream>>>(l, MQ, mwA, mwD, s3i, PS);
    k_final<<<NB, 320, 0, stream>>>(PS, g3w, beta, out);
}

// Round 6
// 93.100 us; speedup vs baseline: 5.8945x; 5.8945x over previous
//
#include <hip/hip_runtime.h>
#include <math.h>

// Fuzzy capsule routing, MI355X — round 6: DS-pipe offload WITHOUT fences.
// mw coefficient rows in global memory (VMEM broadcast, L1/L2-hot); g-reduce +
// row-build done by small dedicated kernels between routing kernels (kernel
// boundaries give cross-XCD visibility; no __threadfence, no atomics).

#define NB 64
#define NK 20
#define NSPLIT 16
#define CPB 2
#define LPST 20           // lp row stride (floats)
#define RST 132           // r_s row stride
#define MROW 20           // mw row: [0..15]=-2Wg, [16]=|g|^2 (pad to 20)
#define QROW 12           // MQ row: [0..9]=W.W^T pairs (pad to 12)

__device__ __forceinline__ float frcp(float x){ return __builtin_amdgcn_rcpf(x); }
__device__ __forceinline__ float4 ldg4(const float* p){ return *(const float4*)p; }

// one mw row for (c,k): dp[0..15] = -2*W.g terms, dp[16] = |g|^2
__device__ __forceinline__ void build_row(const float* __restrict__ W,
                                          const float* g, float* __restrict__ dp)
{
    float w[16];
    {
        float4 a = ldg4(W+0), b = ldg4(W+4), cc = ldg4(W+8), d = ldg4(W+12);
        w[0]=a.x; w[1]=a.y; w[2]=a.z; w[3]=a.w;
        w[4]=b.x; w[5]=b.y; w[6]=b.z; w[7]=b.w;
        w[8]=cc.x; w[9]=cc.y; w[10]=cc.z; w[11]=cc.w;
        w[12]=d.x; w[13]=d.y; w[14]=d.z; w[15]=d.w;
    }
    float out[17];
    #pragma unroll
    for (int i=0;i<4;i++)
        #pragma unroll
        for (int j=0;j<4;j++){
            float a = w[j*4+0]*g[i*4+0] + w[j*4+1]*g[i*4+1]
                    + w[j*4+2]*g[i*4+2] + w[j*4+3]*g[i*4+3];
            out[i*4+j] = -2.f*a;
        }
    float cst = 0.f;
    #pragma unroll
    for (int x=0;x<16;x++) cst += g[x]*g[x];
    out[16] = cst;
    *(float4*)(dp+0)  = make_float4(out[0],out[1],out[2],out[3]);
    *(float4*)(dp+4)  = make_float4(out[4],out[5],out[6],out[7]);
    *(float4*)(dp+8)  = make_float4(out[8],out[9],out[10],out[11]);
    *(float4*)(dp+12) = make_float4(out[12],out[13],out[14],out[15]);
    *(float4*)(dp+16) = make_float4(out[16],0.f,0.f,0.f);
}

// ---------------- prep: mwA from g0; MQ (n==0 blocks) ----------------
__global__ __launch_bounds__(256)
void k_prep(const float* __restrict__ g_in, const float* __restrict__ wgt,
            float* __restrict__ mwA, float* __restrict__ MQ)
{
    const int q = blockIdx.x, n = blockIdx.y, tid = threadIdx.x;
    if (tid >= 160) return;
    const int c = tid/5, kloc = tid - c*5, k = q*5 + kloc;
    const float* W = wgt + k*512 + c*16;
    float g[16];
    {
        const float* gp = g_in + n*320 + k*16;
        float4 a = ldg4(gp+0), b = ldg4(gp+4), cc = ldg4(gp+8), d = ldg4(gp+12);
        g[0]=a.x; g[1]=a.y; g[2]=a.z; g[3]=a.w;
        g[4]=b.x; g[5]=b.y; g[6]=b.z; g[7]=b.w;
        g[8]=cc.x; g[9]=cc.y; g[10]=cc.z; g[11]=cc.w;
        g[12]=d.x; g[13]=d.y; g[14]=d.z; g[15]=d.w;
    }
    build_row(W, g, mwA + (size_t)(n*640 + c*NK + k)*MROW);
    if (n == 0){
        float w[16];
        {
            float4 a = ldg4(W+0), b = ldg4(W+4), cc = ldg4(W+8), d = ldg4(W+12);
            w[0]=a.x; w[1]=a.y; w[2]=a.z; w[3]=a.w;
            w[4]=b.x; w[5]=b.y; w[6]=b.z; w[7]=b.w;
            w[8]=cc.x; w[9]=cc.y; w[10]=cc.z; w[11]=cc.w;
            w[12]=d.x; w[13]=d.y; w[14]=d.z; w[15]=d.w;
        }
        float qv[10]; int p = 0;
        #pragma unroll
        for (int j=0;j<4;j++)
            #pragma unroll
            for (int jp=j;jp<4;jp++){
                float a = w[j*4+0]*w[jp*4+0] + w[j*4+1]*w[jp*4+1]
                        + w[j*4+2]*w[jp*4+2] + w[j*4+3]*w[jp*4+3];
                qv[p++] = (j==jp)? a : 2.f*a;
            }
        float* dp = MQ + (size_t)(c*NK + k)*QROW;
        *(float4*)(dp+0) = make_float4(qv[0],qv[1],qv[2],qv[3]);
        *(float4*)(dp+4) = make_float4(qv[4],qv[5],qv[6],qv[7]);
        *(float4*)(dp+8) = make_float4(qv[8],qv[9],0.f,0.f);
    }
}

// ---------------- reduce: P -> g -> mw rows (+ s3inv, g3w) ----------------
template<int MODE>
__global__ __launch_bounds__(256)
void k_reduce(const float* __restrict__ P, const float* __restrict__ wgt,
              float* __restrict__ mwOut, float* __restrict__ s3inv,
              float* __restrict__ g3w)
{
    const int q = blockIdx.x, n = blockIdx.y, tid = threadIdx.x;
    __shared__ float tmp_s[85];
    __shared__ float g_s[80];
    if (tid < 85){
        float acc = 0.f;
        const float* p = P + (size_t)n*NSPLIT*340 + q*85 + tid;
        #pragma unroll
        for (int s=0;s<NSPLIT;s++) acc += p[s*340];
        tmp_s[tid] = acc;
    }
    __syncthreads();
    if (tid < 80) g_s[tid] = tmp_s[(tid>>4)*17 + (tid&15)] / tmp_s[(tid>>4)*17 + 16];
    if (MODE && tid < 5) s3inv[n*NK + q*5 + tid] = 1.f / tmp_s[tid*17 + 16];
    __syncthreads();
    if (MODE && tid < 80) g3w[n*320 + q*80 + tid] = g_s[tid];
    if (tid < 160){
        const int c = tid/5, kloc = tid - c*5, k = q*5 + kloc;
        build_row(wgt + k*512 + c*16, &g_s[kloc*16],
                  mwOut + (size_t)(n*640 + c*NK + k)*MROW);
    }
}

// ---------------- routing iteration ----------------
__global__ __launch_bounds__(256, 4)
void k_route(const float* __restrict__ l, const float* __restrict__ wgt,
             const float* __restrict__ MQ, const float* __restrict__ mwIn,
             float* __restrict__ P)
{
    const int split = blockIdx.x, n = blockIdx.y, tid = threadIdx.x;
    const int c0 = split*CPB;

    __shared__ __align__(16) float lp_s[CPB*64*LPST];   // 2560
    __shared__ __align__(16) float r_s[NK*RST];         // 2640
    __shared__ __align__(16) float red_s[4*NK*MROW];    // 1600
    __shared__ __align__(16) float wt_s[NK*33];         // 660

    for (int t = tid; t < NK*32; t += 256){
        int k = t>>5, rest = t&31;
        wt_s[k*33 + rest] = wgt[k*512 + c0*16 + rest];
    }
    const float* lsrc = l + ((size_t)n*32 + c0)*1024;
    #pragma unroll
    for (int i=0;i<8;i++){
        int t = i*256 + tid;
        int cl = t>>10, dd = (t>>6)&15, wh = t&63;
        lp_s[(cl*64 + wh)*LPST + dd] = lsrc[t];
    }
    __syncthreads();

    // ---- phase 1: thread=(m, khalf); mw/MQ from global (broadcast) ----
    {
        const int m = tid >> 1, kh = tid & 1;
        const float* lpr = &lp_s[m*LPST];
        float lp[16];
        #pragma unroll
        for (int q=0;q<4;q++){
            float4 v = *(const float4*)&lpr[q*4];
            lp[q*4+0]=v.x; lp[q*4+1]=v.y; lp[q*4+2]=v.z; lp[q*4+3]=v.w;
        }
        float QS[10];
        {
            int p=0;
            #pragma unroll
            for (int j=0;j<4;j++)
                #pragma unroll
                for (int jp=j;jp<4;jp++){
                    QS[p] = lp[j]*lp[jp] + lp[4+j]*lp[4+jp]
                          + lp[8+j]*lp[8+jp] + lp[12+j]*lp[12+jp];
                    p++;
                }
        }
        const int cl = tid >> 7;   // wave-uniform
        const int rb = __builtin_amdgcn_readfirstlane((n*32 + c0 + cl)*NK);
        const int qb = __builtin_amdgcn_readfirstlane((c0 + cl)*NK);
        const float* mwb = mwIn + (size_t)(rb + kh*10)*MROW;
        const float* mqb = MQ   + (size_t)(qb + kh*10)*QROW;
        float invs[10];
        float rd = 0.f;
        #pragma unroll
        for (int i=0;i<10;i++){
            const float* row = mwb + i*MROW;
            const float* mq  = mqb + i*QROW;
            float4 w0 = ldg4(row+0), w1 = ldg4(row+4), w2 = ldg4(row+8), w3 = ldg4(row+12);
            float  c2 = row[16];
            float4 m0 = ldg4(mq+0), m1 = ldg4(mq+4);
            float2 m2 = *(const float2*)(mq+8);
            float rn = c2;
            rn += m0.x*QS[0] + m0.y*QS[1] + m0.z*QS[2] + m0.w*QS[3]
                + m1.x*QS[4] + m1.y*QS[5] + m1.z*QS[6] + m1.w*QS[7]
                + m2.x*QS[8] + m2.y*QS[9];
            rn += w0.x*lp[0] + w0.y*lp[1] + w0.z*lp[2] + w0.w*lp[3]
                + w1.x*lp[4] + w1.y*lp[5] + w1.z*lp[6] + w1.w*lp[7]
                + w2.x*lp[8] + w2.y*lp[9] + w2.z*lp[10]+ w2.w*lp[11]
                + w3.x*lp[12]+ w3.y*lp[13]+ w3.z*lp[14]+ w3.w*lp[15];
            float inv = frcp(rn);
            invs[i] = inv;
            rd += inv;
        }
        rd += __shfl_xor(rd, 1, 64);
        float ird = frcp(rd);
        #pragma unroll
        for (int i=0;i<10;i++){
            float t0 = invs[i]*ird;
            r_s[(kh*10+i)*RST + m] = t0*t0;
        }
    }
    __syncthreads();

    // ---- phase 3: T[w,k,ij] = sum_m r*lp ----
    const int k3 = tid & 31, mi = tid >> 5;
    const int kk = (k3 < NK)? k3 : k3 - NK;
    const int mbase = mi*16;
    float T[16]; float sacc = 0.f;
    #pragma unroll
    for (int d=0;d<16;d++) T[d]=0.f;

    auto acc_m = [&](float r, int m){
        const float* lr = &lp_s[m*LPST];
        float4 v0 = *(const float4*)&lr[0];
        float4 v1 = *(const float4*)&lr[4];
        float4 v2 = *(const float4*)&lr[8];
        float4 v3 = *(const float4*)&lr[12];
        T[0]+=r*v0.x; T[1]+=r*v0.y; T[2]+=r*v0.z; T[3]+=r*v0.w;
        T[4]+=r*v1.x; T[5]+=r*v1.y; T[6]+=r*v1.z; T[7]+=r*v1.w;
        T[8]+=r*v2.x; T[9]+=r*v2.y; T[10]+=r*v2.z; T[11]+=r*v2.w;
        T[12]+=r*v3.x; T[13]+=r*v3.y; T[14]+=r*v3.z; T[15]+=r*v3.w;
        sacc += r;
    };
    #pragma unroll
    for (int j4=0;j4<4;j4++){
        float4 rv = *(const float4*)&r_s[kk*RST + mbase + j4*4];
        acc_m(rv.x, mbase + j4*4 + 0);
        acc_m(rv.y, mbase + j4*4 + 1);
        acc_m(rv.z, mbase + j4*4 + 2);
        acc_m(rv.w, mbase + j4*4 + 3);
    }
    #pragma unroll
    for (int d=0;d<16;d++) T[d] += __shfl_xor(T[d], 32, 64);
    sacc += __shfl_xor(sacc, 32, 64);
    if ((k3 < NK) && !(tid & 32)){
        float* row = &red_s[((tid>>6)*NK + k3)*MROW];
        *(float4*)(row+0)  = make_float4(T[0],T[1],T[2],T[3]);
        *(float4*)(row+4)  = make_float4(T[4],T[5],T[6],T[7]);
        *(float4*)(row+8)  = make_float4(T[8],T[9],T[10],T[11]);
        *(float4*)(row+12) = make_float4(T[12],T[13],T[14],T[15]);
        row[16] = sacc;
    }
    __syncthreads();

    // ---- u-contract + P write ----
    for (int t = tid; t < NK*17; t += 256){
        int k = t/17, x = t - k*17;
        float acc = 0.f;
        if (x == 16){
            #pragma unroll
            for (int w=0;w<4;w++) acc += red_s[(w*NK+k)*MROW + 16];
        } else {
            int i = x>>2, o = x&3;
            #pragma unroll
            for (int w=0;w<4;w++){
                int cl = w>>1;
                #pragma unroll
                for (int j=0;j<4;j++)
                    acc += red_s[(w*NK+k)*MROW + i*4+j] * wt_s[k*33 + cl*16 + j*4+o];
            }
        }
        P[(size_t)(n*NSPLIT+split)*340 + t] = acc;
    }
}

// ---------------- sigma pass ----------------
__global__ __launch_bounds__(256, 4)
void k_sigma(const float* __restrict__ l, const float* __restrict__ MQ,
             const float* __restrict__ mw2, const float* __restrict__ mwD,
             const float* __restrict__ s3inv, float* __restrict__ PS)
{
    const int split = blockIdx.x, n = blockIdx.y, tid = threadIdx.x;
    const int c0 = split*CPB;

    __shared__ __align__(16) float lp_s[CPB*64*LPST];
    __shared__ __align__(16) float pr_s[NK*RST];
    __shared__ __align__(16) float red2[4*NK];

    const float* lsrc = l + ((size_t)n*32 + c0)*1024;
    #pragma unroll
    for (int i=0;i<8;i++){
        int t = i*256 + tid;
        int cl = t>>10, dd = (t>>6)&15, wh = t&63;
        lp_s[(cl*64 + wh)*LPST + dd] = lsrc[t];
    }
    __syncthreads();

    // ---- phase 1: r (g2-rows) and dist3 (g3-rows); store r*dist3 ----
    {
        const int m = tid >> 1, kh = tid & 1;
        const float* lpr = &lp_s[m*LPST];
        float lp[16];
        #pragma unroll
        for (int q=0;q<4;q++){
            float4 v = *(const float4*)&lpr[q*4];
            lp[q*4+0]=v.x; lp[q*4+1]=v.y; lp[q*4+2]=v.z; lp[q*4+3]=v.w;
        }
        float QS[10];
        {
            int p=0;
            #pragma unroll
            for (int j=0;j<4;j++)
                #pragma unroll
                for (int jp=j;jp<4;jp++){
                    QS[p] = lp[j]*lp[jp] + lp[4+j]*lp[4+jp]
                          + lp[8+j]*lp[8+jp] + lp[12+j]*lp[12+jp];
                    p++;
                }
        }
        const int cl = tid >> 7;
        const int rb = __builtin_amdgcn_readfirstlane((n*32 + c0 + cl)*NK);
        const int qb = __builtin_amdgcn_readfirstlane((c0 + cl)*NK);
        const float* m2b = mw2 + (size_t)(rb + kh*10)*MROW;
        const float* mDb = mwD + (size_t)(rb + kh*10)*MROW;
        const float* mqb = MQ  + (size_t)(qb + kh*10)*QROW;
        float invs[10], d3s[10];
        float rd = 0.f;
        #pragma unroll
        for (int i=0;i<10;i++){
            const float* r2 = m2b + i*MROW;
            const float* rD = mDb + i*MROW;
            const float* mq = mqb + i*QROW;
            float4 m0 = ldg4(mq+0), m1 = ldg4(mq+4);
            float2 m2v = *(const float2*)(mq+8);
            float qv = m0.x*QS[0] + m0.y*QS[1] + m0.z*QS[2] + m0.w*QS[3]
                     + m1.x*QS[4] + m1.y*QS[5] + m1.z*QS[6] + m1.w*QS[7]
                     + m2v.x*QS[8] + m2v.y*QS[9];
            float4 a0 = ldg4(r2+0), a1 = ldg4(r2+4), a2 = ldg4(r2+8), a3 = ldg4(r2+12);
            float rn = r2[16] + qv
                + a0.x*lp[0] + a0.y*lp[1] + a0.z*lp[2] + a0.w*lp[3]
                + a1.x*lp[4] + a1.y*lp[5] + a1.z*lp[6] + a1.w*lp[7]
                + a2.x*lp[8] + a2.y*lp[9] + a2.z*lp[10]+ a2.w*lp[11]
                + a3.x*lp[12]+ a3.y*lp[13]+ a3.z*lp[14]+ a3.w*lp[15];
            float4 b0 = ldg4(rD+0), b1 = ldg4(rD+4), b2 = ldg4(rD+8), b3 = ldg4(rD+12);
            float d3 = rD[16] + qv
                + b0.x*lp[0] + b0.y*lp[1] + b0.z*lp[2] + b0.w*lp[3]
                + b1.x*lp[4] + b1.y*lp[5] + b1.z*lp[6] + b1.w*lp[7]
                + b2.x*lp[8] + b2.y*lp[9] + b2.z*lp[10]+ b2.w*lp[11]
                + b3.x*lp[12]+ b3.y*lp[13]+ b3.z*lp[14]+ b3.w*lp[15];
            float inv = frcp(rn);
            invs[i] = inv; d3s[i] = d3;
            rd += inv;
        }
        rd += __shfl_xor(rd, 1, 64);
        float ird = frcp(rd);
        #pragma unroll
        for (int i=0;i<10;i++){
            float t0 = invs[i]*ird;
            pr_s[(kh*10+i)*RST + m] = (t0*t0)*d3s[i];
        }
    }
    __syncthreads();

    // ---- phase 3: per-k sum ----
    const int k3 = tid & 31, mi = tid >> 5;
    const int kk = (k3 < NK)? k3 : k3 - NK;
    float sig = 0.f;
    #pragma unroll
    for (int j4=0;j4<4;j4++){
        float4 rv = *(const float4*)&pr_s[kk*RST + mi*16 + j4*4];
        sig += rv.x + rv.y + rv.z + rv.w;
    }
    sig += __shfl_xor(sig, 32, 64);
    if ((k3 < NK) && !(tid & 32)) red2[(tid>>6)*NK + k3] = sig;
    __syncthreads();
    if (tid < NK){
        float acc = red2[tid] + red2[NK+tid] + red2[2*NK+tid] + red2[3*NK+tid];
        PS[(n*NSPLIT+split)*NK + tid] = acc * s3inv[n*NK + tid];
    }
}

// ---------------- finalize ----------------
__global__ __launch_bounds__(320)
void k_final(const float* __restrict__ PS, const float* __restrict__ g3w,
             const float* __restrict__ beta, float* __restrict__ out)
{
    const int n = blockIdx.x, tid = threadIdx.x;
    out[1280 + n*320 + tid] = g3w[n*320 + tid];
    if (tid < NK){
        float acc = 0.f;
        #pragma unroll
        for (int s=0;s<NSPLIT;s++) acc += PS[(n*NSPLIT+s)*NK + tid];
        float z = beta[tid] - 0.5f*logf(acc);   // LAMBDA = 1
        out[n*NK + tid] = 1.f/(1.f + expf(-z));
    }
}

extern "C" void kernel_launch(void* const* d_in, const int* in_sizes, int n_in,
                              void* d_out, int out_size, void* d_ws, size_t ws_size,
                              hipStream_t stream)
{
    const float* l    = (const float*)d_in[0];
    const float* g    = (const float*)d_in[1];
    const float* wgt  = (const float*)d_in[2];
    const float* beta = (const float*)d_in[3];
    float* out = (float*)d_out;
    float* ws  = (float*)d_ws;

    const size_t PSZ  = (size_t)NB * NSPLIT * 340;      // 348160
    const size_t MWSZ = (size_t)NB * 640 * MROW;        // 819200
    float* P    = ws;
    float* mwA  = P    + PSZ;
    float* mwB  = mwA  + MWSZ;
    float* MQ   = mwB  + MWSZ;                          // 7680
    float* s3i  = MQ   + 7680;                          // 1280
    float* g3w  = s3i  + 1280;                          // 20480
    float* PS   = g3w  + 20480;                         // 20480

    dim3 gridR(NSPLIT, NB), gridS(4, NB), blk(256);
    k_prep<<<gridS, blk, 0, stream>>>(g, wgt, mwA, MQ);
    k_route<<<gridR, blk, 0, stream>>>(l, wgt, MQ, mwA, P);          // r1 (g0)
    k_reduce<0><<<gridS, blk, 0, stream>>>(P, wgt, mwB, nullptr, nullptr);  // g1
    k_route<<<gridR, blk, 0, stream>>>(l, wgt, MQ, mwB, P);          // r2 (g1)
    k_reduce<0><<<gridS, blk, 0, stream>>>(P, wgt, mwA, nullptr, nullptr);  // g2
    k_route<<<gridR, blk, 0, stream>>>(l, wgt, MQ, mwA, P);          // r3 (g2)
    k_reduce<1><<<gridS, blk, 0, stream>>>(P, wgt, mwB, s3i, g3w);          // g3
    k_sigma<<<gridR, blk, 0, stream>>>(l, MQ, mwA, mwB, s3i, PS);
    k_final<<<NB, 320, 0, stream>>>(PS, g3w, beta, out);
}

// Round 8
// 51.688 us; speedup vs baseline: 10.6170x; 1.8012x over previous
//
#include <hip/hip_runtime.h>
#include <math.h>

// Fuzzy capsule routing, MI355X — round 7 (resubmit after infra failure):
// sigma pass eliminated via sigma = (sum_m r*||V||^2)/s - ||g3||^2
// (rqv accumulated in route 3). 7 launches, 3 heavy. mw/MQ rows in global,
// staged to LDS per block.

#define NB 64
#define NK 20
#define NSPLIT 16
#define CPB 2
#define LPST 20           // lp row stride (floats)
#define RST 132           // r_s row stride
#define MROW 20           // mw row: [0..15]=-2Wg, [16]=|g|^2 (pad 20)
#define QROW 12           // MQ row: [0..9]=W.W^T pairs (pad 12)
#define WST 36            // wt_s row stride (16B-aligned)
#define PROW 18           // P row per k: [0..15]=u, [16]=s, [17]=rqv

__device__ __forceinline__ float frcp(float x){ return __builtin_amdgcn_rcpf(x); }
__device__ __forceinline__ float4 ldg4(const float* p){ return *(const float4*)p; }

// one mw row for (c,k): dp[0..15] = -2*W.g, dp[16] = |g|^2
__device__ __forceinline__ void build_row(const float* __restrict__ W,
                                          const float* g, float* __restrict__ dp)
{
    float w[16];
    {
        float4 a = ldg4(W+0), b = ldg4(W+4), cc = ldg4(W+8), d = ldg4(W+12);
        w[0]=a.x; w[1]=a.y; w[2]=a.z; w[3]=a.w;
        w[4]=b.x; w[5]=b.y; w[6]=b.z; w[7]=b.w;
        w[8]=cc.x; w[9]=cc.y; w[10]=cc.z; w[11]=cc.w;
        w[12]=d.x; w[13]=d.y; w[14]=d.z; w[15]=d.w;
    }
    float out[17];
    #pragma unroll
    for (int i=0;i<4;i++)
        #pragma unroll
        for (int j=0;j<4;j++){
            float a = w[j*4+0]*g[i*4+0] + w[j*4+1]*g[i*4+1]
                    + w[j*4+2]*g[i*4+2] + w[j*4+3]*g[i*4+3];
            out[i*4+j] = -2.f*a;
        }
    float cst = 0.f;
    #pragma unroll
    for (int x=0;x<16;x++) cst += g[x]*g[x];
    out[16] = cst;
    *(float4*)(dp+0)  = make_float4(out[0],out[1],out[2],out[3]);
    *(float4*)(dp+4)  = make_float4(out[4],out[5],out[6],out[7]);
    *(float4*)(dp+8)  = make_float4(out[8],out[9],out[10],out[11]);
    *(float4*)(dp+12) = make_float4(out[12],out[13],out[14],out[15]);
    *(float4*)(dp+16) = make_float4(out[16],0.f,0.f,0.f);
}

// ---------------- prep: mwA from g0 for all n; MQ once ----------------
__global__ __launch_bounds__(256)
void k_prep(const float* __restrict__ g_in, const float* __restrict__ wgt,
            float* __restrict__ mwA, float* __restrict__ MQ)
{
    const int q = blockIdx.x, n = blockIdx.y, tid = threadIdx.x;
    if (tid >= 160) return;
    const int c = tid/5, kloc = tid - c*5, k = q*5 + kloc;
    const float* W = wgt + k*512 + c*16;
    float g[16];
    {
        const float* gp = g_in + n*320 + k*16;
        float4 a = ldg4(gp+0), b = ldg4(gp+4), cc = ldg4(gp+8), d = ldg4(gp+12);
        g[0]=a.x; g[1]=a.y; g[2]=a.z; g[3]=a.w;
        g[4]=b.x; g[5]=b.y; g[6]=b.z; g[7]=b.w;
        g[8]=cc.x; g[9]=cc.y; g[10]=cc.z; g[11]=cc.w;
        g[12]=d.x; g[13]=d.y; g[14]=d.z; g[15]=d.w;
    }
    build_row(W, g, mwA + (size_t)(n*640 + c*NK + k)*MROW);
    if (n == 0){
        float w[16];
        {
            float4 a = ldg4(W+0), b = ldg4(W+4), cc = ldg4(W+8), d = ldg4(W+12);
            w[0]=a.x; w[1]=a.y; w[2]=a.z; w[3]=a.w;
            w[4]=b.x; w[5]=b.y; w[6]=b.z; w[7]=b.w;
            w[8]=cc.x; w[9]=cc.y; w[10]=cc.z; w[11]=cc.w;
            w[12]=d.x; w[13]=d.y; w[14]=d.z; w[15]=d.w;
        }
        float qv[10]; int p = 0;
        #pragma unroll
        for (int j=0;j<4;j++)
            #pragma unroll
            for (int jp=j;jp<4;jp++){
                float a = w[j*4+0]*w[jp*4+0] + w[j*4+1]*w[jp*4+1]
                        + w[j*4+2]*w[jp*4+2] + w[j*4+3]*w[jp*4+3];
                qv[p++] = (j==jp)? a : 2.f*a;
            }
        float* dp = MQ + (size_t)(c*NK + k)*QROW;
        *(float4*)(dp+0) = make_float4(qv[0],qv[1],qv[2],qv[3]);
        *(float4*)(dp+4) = make_float4(qv[4],qv[5],qv[6],qv[7]);
        *(float4*)(dp+8) = make_float4(qv[8],qv[9],0.f,0.f);
    }
}

// ---------------- reduce: P -> g -> next mw rows ----------------
__global__ __launch_bounds__(256)
void k_reduce(const float* __restrict__ P, const float* __restrict__ wgt,
              float* __restrict__ mwOut)
{
    const int q = blockIdx.x, n = blockIdx.y, tid = threadIdx.x;
    __shared__ float tmp_s[5*PROW];
    __shared__ float g_s[80];
    if (tid < 5*PROW){
        float acc = 0.f;
        const float* p = P + (size_t)n*NSPLIT*NK*PROW + q*5*PROW + tid;
        #pragma unroll
        for (int s=0;s<NSPLIT;s++) acc += p[s*NK*PROW];
        tmp_s[tid] = acc;
    }
    __syncthreads();
    if (tid < 80){
        int kloc = tid>>4, d = tid&15;
        g_s[tid] = tmp_s[kloc*PROW + d] / tmp_s[kloc*PROW + 16];
    }
    __syncthreads();
    if (tid < 160){
        const int c = tid/5, kloc = tid - c*5, k = q*5 + kloc;
        build_row(wgt + k*512 + c*16, &g_s[kloc*16],
                  mwOut + (size_t)(n*640 + c*NK + k)*MROW);
    }
}

// ---------------- final reduce: g3, sigma, a ----------------
__global__ __launch_bounds__(256)
void k_redfinal(const float* __restrict__ P, const float* __restrict__ beta,
                float* __restrict__ out)
{
    const int q = blockIdx.x, n = blockIdx.y, tid = threadIdx.x;
    __shared__ float tmp_s[5*PROW];
    if (tid < 5*PROW){
        float acc = 0.f;
        const float* p = P + (size_t)n*NSPLIT*NK*PROW + q*5*PROW + tid;
        #pragma unroll
        for (int s=0;s<NSPLIT;s++) acc += p[s*NK*PROW];
        tmp_s[tid] = acc;
    }
    __syncthreads();
    if (tid < 80){
        int kloc = tid>>4, d = tid&15;
        out[1280 + n*320 + q*80 + tid] = tmp_s[kloc*PROW + d] / tmp_s[kloc*PROW + 16];
    }
    if (tid < 5){
        const int k = q*5 + tid;
        float s   = tmp_s[tid*PROW + 16];
        float rqv = tmp_s[tid*PROW + 17];
        float usq = 0.f;
        #pragma unroll
        for (int d=0;d<16;d++){ float u = tmp_s[tid*PROW + d]; usq += u*u; }
        float is = 1.f/s;
        float sig = is*rqv - (is*is)*usq;     // (1/s)Sum r|V|^2 - |g3|^2
        float z = beta[k] - 0.5f*logf(sig);   // LAMBDA = 1
        out[n*NK + k] = 1.f/(1.f + expf(-z));
    }
}

// ---------------- routing iteration (MODE1: also accumulate rqv) ----------------
template<int MODE>
__global__ __launch_bounds__(256, MODE?3:4)
void k_route(const float* __restrict__ l, const float* __restrict__ wgt,
             const float* __restrict__ MQ, const float* __restrict__ mwIn,
             float* __restrict__ P)
{
    const int split = blockIdx.x, n = blockIdx.y, tid = threadIdx.x;
    const int c0 = split*CPB;

    __shared__ __align__(16) float lp_s[CPB*64*LPST];     // 2560
    __shared__ __align__(16) float r_s[NK*RST];           // 2640
    __shared__ __align__(16) float rqv_s[MODE? NK*RST:4]; // 2640 (MODE1)
    __shared__ __align__(16) float mw_s[2*NK*MROW];       // 800
    __shared__ __align__(16) float mq_s[2*NK*QROW];       // 480
    __shared__ __align__(16) float wt_s[NK*WST];          // 720
    __shared__ __align__(16) float red_s[4*NK*MROW];      // 1600

    // ---- stage: lp, mw rows, MQ rows, W ----
    const float* lsrc = l + ((size_t)n*32 + c0)*1024;
    #pragma unroll
    for (int i=0;i<8;i++){
        int t = i*256 + tid;
        int cl = t>>10, dd = (t>>6)&15, wh = t&63;
        lp_s[(cl*64 + wh)*LPST + dd] = lsrc[t];
    }
    {
        const float* msrc = mwIn + (size_t)(n*640 + c0*NK)*MROW;   // 800 contig
        if (tid < 200) *(float4*)&mw_s[tid*4] = ldg4(msrc + tid*4);
        const float* qsrc = MQ + (size_t)(c0*NK)*QROW;             // 480 contig
        if (tid < 120) *(float4*)&mq_s[tid*4] = ldg4(qsrc + tid*4);
        if (tid < 160){
            int k = tid>>3, part = tid&7, cl = part>>2, quad = part&3;
            *(float4*)&wt_s[k*WST + cl*16 + quad*4] =
                ldg4(wgt + k*512 + (c0+cl)*16 + quad*4);
        }
    }
    __syncthreads();

    // ---- phase 1: thread=(m, khalf); 10 k each ----
    {
        const int m = tid >> 1, kh = tid & 1;
        const float* lpr = &lp_s[m*LPST];
        float lp[16];
        #pragma unroll
        for (int q=0;q<4;q++){
            float4 v = *(const float4*)&lpr[q*4];
            lp[q*4+0]=v.x; lp[q*4+1]=v.y; lp[q*4+2]=v.z; lp[q*4+3]=v.w;
        }
        float QS[10];
        {
            int p=0;
            #pragma unroll
            for (int j=0;j<4;j++)
                #pragma unroll
                for (int jp=j;jp<4;jp++){
                    QS[p] = lp[j]*lp[jp] + lp[4+j]*lp[4+jp]
                          + lp[8+j]*lp[8+jp] + lp[12+j]*lp[12+jp];
                    p++;
                }
        }
        const int cl = tid >> 7;   // wave-uniform
        const float* mwb = &mw_s[(cl*NK + kh*10)*MROW];
        const float* mqb = &mq_s[(cl*NK + kh*10)*QROW];
        float invs[10], qvs[10];
        float rd = 0.f;
        #pragma unroll
        for (int i=0;i<10;i++){
            const float* row = mwb + i*MROW;
            const float* mq  = mqb + i*QROW;
            float4 m0 = *(const float4*)(mq+0);
            float4 m1 = *(const float4*)(mq+4);
            float2 m2 = *(const float2*)(mq+8);
            float qv = m0.x*QS[0] + m0.y*QS[1] + m0.z*QS[2] + m0.w*QS[3]
                     + m1.x*QS[4] + m1.y*QS[5] + m1.z*QS[6] + m1.w*QS[7]
                     + m2.x*QS[8] + m2.y*QS[9];
            float4 w0 = *(const float4*)(row+0);
            float4 w1 = *(const float4*)(row+4);
            float4 w2 = *(const float4*)(row+8);
            float4 w3 = *(const float4*)(row+12);
            float rn = row[16] + qv
                + w0.x*lp[0] + w0.y*lp[1] + w0.z*lp[2] + w0.w*lp[3]
                + w1.x*lp[4] + w1.y*lp[5] + w1.z*lp[6] + w1.w*lp[7]
                + w2.x*lp[8] + w2.y*lp[9] + w2.z*lp[10]+ w2.w*lp[11]
                + w3.x*lp[12]+ w3.y*lp[13]+ w3.z*lp[14]+ w3.w*lp[15];
            float inv = frcp(rn);
            invs[i] = inv;
            if (MODE) qvs[i] = qv;
            rd += inv;
        }
        rd += __shfl_xor(rd, 1, 64);
        float ird = frcp(rd);
        #pragma unroll
        for (int i=0;i<10;i++){
            float t0 = invs[i]*ird;
            float r  = t0*t0;
            r_s[(kh*10+i)*RST + m] = r;
            if (MODE) rqv_s[(kh*10+i)*RST + m] = r*qvs[i];
        }
    }
    __syncthreads();

    // ---- phase 3: T[w,k,ij] = sum_m r*lp (+ rqv sum) ----
    const int k3 = tid & 31, mi = tid >> 5;
    const int kk = (k3 < NK)? k3 : k3 - NK;
    const int mbase = mi*16;
    float T[16]; float sacc = 0.f, rq = 0.f;
    #pragma unroll
    for (int d=0;d<16;d++) T[d]=0.f;

    auto acc_m = [&](float r, int m){
        const float* lr = &lp_s[m*LPST];
        float4 v0 = *(const float4*)&lr[0];
        float4 v1 = *(const float4*)&lr[4];
        float4 v2 = *(const float4*)&lr[8];
        float4 v3 = *(const float4*)&lr[12];
        T[0]+=r*v0.x; T[1]+=r*v0.y; T[2]+=r*v0.z; T[3]+=r*v0.w;
        T[4]+=r*v1.x; T[5]+=r*v1.y; T[6]+=r*v1.z; T[7]+=r*v1.w;
        T[8]+=r*v2.x; T[9]+=r*v2.y; T[10]+=r*v2.z; T[11]+=r*v2.w;
        T[12]+=r*v3.x; T[13]+=r*v3.y; T[14]+=r*v3.z; T[15]+=r*v3.w;
        sacc += r;
    };
    #pragma unroll
    for (int j4=0;j4<4;j4++){
        float4 rv = *(const float4*)&r_s[kk*RST + mbase + j4*4];
        acc_m(rv.x, mbase + j4*4 + 0);
        acc_m(rv.y, mbase + j4*4 + 1);
        acc_m(rv.z, mbase + j4*4 + 2);
        acc_m(rv.w, mbase + j4*4 + 3);
        if (MODE){
            float4 qv4 = *(const float4*)&rqv_s[kk*RST + mbase + j4*4];
            rq += qv4.x + qv4.y + qv4.z + qv4.w;
        }
    }
    #pragma unroll
    for (int d=0;d<16;d++) T[d] += __shfl_xor(T[d], 32, 64);
    sacc += __shfl_xor(sacc, 32, 64);
    if (MODE) rq += __shfl_xor(rq, 32, 64);
    if ((k3 < NK) && !(tid & 32)){
        float* row = &red_s[((tid>>6)*NK + k3)*MROW];
        *(float4*)(row+0)  = make_float4(T[0],T[1],T[2],T[3]);
        *(float4*)(row+4)  = make_float4(T[4],T[5],T[6],T[7]);
        *(float4*)(row+8)  = make_float4(T[8],T[9],T[10],T[11]);
        *(float4*)(row+12) = make_float4(T[12],T[13],T[14],T[15]);
        row[16] = sacc;
        row[17] = MODE? rq : 0.f;
    }
    __syncthreads();

    // ---- u-contract + P write (rows of PROW=18 per k) ----
    for (int t = tid; t < NK*PROW; t += 256){
        int k = t/PROW, x = t - k*PROW;
        float acc = 0.f;
        if (x >= 16){
            #pragma unroll
            for (int w=0;w<4;w++) acc += red_s[(w*NK+k)*MROW + x];
        } else {
            int i = x>>2, o = x&3;
            #pragma unroll
            for (int w=0;w<4;w++){
                int cl = w>>1;
                #pragma unroll
                for (int j=0;j<4;j++)
                    acc += red_s[(w*NK+k)*MROW + i*4+j] * wt_s[k*WST + cl*16 + j*4+o];
            }
        }
        P[(size_t)(n*NSPLIT+split)*NK*PROW + t] = acc;
    }
}

extern "C" void kernel_launch(void* const* d_in, const int* in_sizes, int n_in,
                              void* d_out, int out_size, void* d_ws, size_t ws_size,
                              hipStream_t stream)
{
    const float* l    = (const float*)d_in[0];
    const float* g    = (const float*)d_in[1];
    const float* wgt  = (const float*)d_in[2];
    const float* beta = (const float*)d_in[3];
    float* out = (float*)d_out;
    float* ws  = (float*)d_ws;

    const size_t PSZ  = (size_t)NB * NSPLIT * NK * PROW;  // 368640
    const size_t MWSZ = (size_t)NB * 640 * MROW;          // 819200
    float* P    = ws;
    float* mwA  = P    + PSZ;
    float* mwB  = mwA  + MWSZ;
    float* MQ   = mwB  + MWSZ;                            // 7680

    dim3 gridR(NSPLIT, NB), gridS(4, NB), blk(256);
    k_prep<<<gridS, blk, 0, stream>>>(g, wgt, mwA, MQ);
    k_route<0><<<gridR, blk, 0, stream>>>(l, wgt, MQ, mwA, P);   // r1 (g0)
    k_reduce<<<gridS, blk, 0, stream>>>(P, wgt, mwB);            // g1 -> mwB
    k_route<0><<<gridR, blk, 0, stream>>>(l, wgt, MQ, mwB, P);   // r2 (g1)
    k_reduce<<<gridS, blk, 0, stream>>>(P, wgt, mwA);            // g2 -> mwA
    k_route<1><<<gridR, blk, 0, stream>>>(l, wgt, MQ, mwA, P);   // r3 (g2) + rqv
    k_redfinal<<<gridS, blk, 0, stream>>>(P, beta, out);         // g3, sigma, a
}